// Round 3
// baseline (546.650 us; speedup 1.0000x reference)
//
#include <hip/hip_runtime.h>
#include <cstddef>

#define Bn 256
#define Hd 128
#define Nd 2048
#define K3 384     // W row stride (3H)

typedef _Float16 half8 __attribute__((ext_vector_type(8)));
typedef float    float4v __attribute__((ext_vector_type(4)));

__device__ __forceinline__ float fast_tanh(float x) {
    // tanh(x) = 1 - 2/(exp(2x)+1); saturates correctly at +/-inf
    return 1.0f - __fdividef(2.0f, __expf(2.0f * x) + 1.0f);
}

// ---------------------------------------------------------------------------
// prep 1: Wf[h][k] = fp16(W[h][k]) for k<256  (static+dynamic columns)
__global__ void prep_w16(const float* __restrict__ W, _Float16* __restrict__ Wf) {
    int idx = blockIdx.x * 256 + threadIdx.x;   // 0..32767
    int h = idx >> 8, k = idx & 255;
    Wf[idx] = (_Float16)W[h * K3 + k];
}

// prep 2: c[b][h] = sum_k W[h][256+k] * dec[b][k]  (decoder term, fp32 exact)
__global__ void prep_c(const float* __restrict__ W, const float* __restrict__ dec,
                       float* __restrict__ cb) {
    __shared__ float dl[Hd];
    int b = blockIdx.x;
    int h = threadIdx.x;       // 128 threads
    dl[h] = dec[b * Hd + h];
    __syncthreads();
    float acc = 0.f;
    #pragma unroll 8
    for (int k = 0; k < Hd; ++k)
        acc = fmaf(W[h * K3 + 256 + k], dl[k], acc);
    cb[b * Hd + h] = acc;
}

// ---------------------------------------------------------------------------
// Main: block = (b, 128-n tile), 256 threads = 4 waves.
// K=256 split into two K=128 phases (static, dynamic) sharing ONE 32 KB LDS
// buffer -> 3 blocks/CU (launch_bounds VGPR cap 170). Wave w owns h in
// [32w,32w+32) as 2 MFMA M-tiles x 8 N-tiles, mfma_f32_16x16x32_f16.
// LDS image: xl[row=n][k], fp16, 128x128, 16B-chunk XOR swizzle:
//   phys_chunk = ck ^ (row & 15) ^ (row >> 4)   (8 bank-cycles per b128 op,
// verified conflict-free for both the staging writes and B-fragment reads).
__global__ __launch_bounds__(256, 3)
void score_kernel(const float* __restrict__ shp, const float* __restrict__ dhp,
                  const _Float16* __restrict__ Wf, const float* __restrict__ cbp,
                  const float* __restrict__ v, float* __restrict__ out) {
    __shared__ __align__(16) _Float16 xl[128 * 128];   // 32 KB, swizzled
    __shared__ float red[4 * 128];

    const int tid  = threadIdx.x;
    const int w    = __builtin_amdgcn_readfirstlane(tid >> 6);  // wave id (SGPR)
    const int lane = tid & 63;
    const int qd   = lane >> 4;       // quad 0..3
    const int ln   = lane & 15;
    const int b    = blockIdx.y;
    const int n0   = blockIdx.x * 128;
    const int h0   = w * 32;

    // staging lane decomposition: 32 n-positions x 2 k-bands
    const int nn = lane & 31;         // col group: cols 4nn..4nn+3
    const int kk = lane >> 5;         // k band 0/1 (+8 rows)

    // ---- acc init with decoder term: D row = quad*4 + reg
    float4v acc[2][8];
    #pragma unroll
    for (int Mt = 0; Mt < 2; ++Mt) {
        float4v c4 = *reinterpret_cast<const float4v*>(cbp + b * Hd + h0 + Mt * 16 + qd * 4);
        #pragma unroll
        for (int Nt = 0; Nt < 8; ++Nt) acc[Mt][Nt] = c4;
    }

    for (int half = 0; half < 2; ++half) {
        const float* src = (half ? dhp : shp) + (size_t)b * (Hd * (size_t)Nd) + n0;
        if (half) __syncthreads();    // WAR: previous phase's LDS reads done

        // ---- stage this wave's 32 k-rows: global [k][n] fp32 -> LDS [n][k] fp16
        #pragma unroll
        for (int g = 0; g < 2; ++g) {
            const int kl = w * 32 + g * 16 + kk * 8;   // 8-row band for this lane
            float4v xv[8];
            #pragma unroll
            for (int j = 0; j < 8; ++j)
                xv[j] = *reinterpret_cast<const float4v*>(src + (size_t)(kl + j) * Nd + 4 * nn);
            const int ck = kl >> 3;                    // 16B chunk index in row
            #pragma unroll
            for (int r = 0; r < 4; ++r) {
                half8 e;
                #pragma unroll
                for (int j = 0; j < 8; ++j) e[j] = (_Float16)xv[j][r];
                const int row  = 4 * nn + r;
                const int phys = ck ^ (row & 15) ^ (row >> 4);
                *reinterpret_cast<half8*>(&xl[row * 128 + phys * 8]) = e;
            }
        }

        // ---- A fragments for this half (L2-hot, independent of staging)
        half8 Af[2][4];
        #pragma unroll
        for (int Mt = 0; Mt < 2; ++Mt) {
            const _Float16* wp = Wf + ((h0 + Mt * 16 + ln) << 8) + half * 128 + qd * 8;
            #pragma unroll
            for (int kt = 0; kt < 4; ++kt)
                Af[Mt][kt] = *reinterpret_cast<const half8*>(wp + kt * 32);
        }
        __syncthreads();

        // ---- MFMA: B[k=quad*8+j][n=lane&15]
        #pragma unroll
        for (int kt = 0; kt < 4; ++kt) {
            half8 Bf[8];
            #pragma unroll
            for (int Nt = 0; Nt < 8; ++Nt) {
                const int row  = Nt * 16 + ln;
                const int phys = (kt * 4 + qd) ^ ln ^ Nt;
                Bf[Nt] = *reinterpret_cast<const half8*>(&xl[row * 128 + phys * 8]);
            }
            #pragma unroll
            for (int Nt = 0; Nt < 8; ++Nt) {
                acc[0][Nt] = __builtin_amdgcn_mfma_f32_16x16x32_f16(Af[0][kt], Bf[Nt], acc[0][Nt], 0, 0, 0);
                acc[1][Nt] = __builtin_amdgcn_mfma_f32_16x16x32_f16(Af[1][kt], Bf[Nt], acc[1][Nt], 0, 0, 0);
            }
        }
    }

    // ---- epilogue: score[n] = sum_m v[m] * tanh(t[m][n])
    float4v v0 = *reinterpret_cast<const float4v*>(v + h0 + qd * 4);
    float4v v1 = *reinterpret_cast<const float4v*>(v + h0 + 16 + qd * 4);
    #pragma unroll
    for (int Nt = 0; Nt < 8; ++Nt) {
        float part = 0.f;
        #pragma unroll
        for (int r = 0; r < 4; ++r) {
            part = fmaf(v0[r], fast_tanh(acc[0][Nt][r]), part);
            part = fmaf(v1[r], fast_tanh(acc[1][Nt][r]), part);
        }
        part += __shfl_xor(part, 16);   // sum quads (same n)
        part += __shfl_xor(part, 32);
        if (qd == 0) red[w * 128 + Nt * 16 + ln] = part;
    }
    __syncthreads();
    if (tid < 128) {
        float s = red[tid] + red[128 + tid] + red[256 + tid] + red[384 + tid];
        out[(size_t)b * Nd + n0 + tid] = s;
    }
}

// ---------------------------------------------------------------------------
// softmax over n=2048 per b, in place. (validated round 1)
__global__ void softmax_k(float* __restrict__ out) {
    int b = blockIdx.x;
    float* row = out + (size_t)b * Nd;
    int tid = threadIdx.x;

    float loc[8];
    float mx = -3.4e38f;
    #pragma unroll
    for (int i = 0; i < 8; ++i) {
        loc[i] = row[tid + (i << 8)];
        mx = fmaxf(mx, loc[i]);
    }
    #pragma unroll
    for (int off = 32; off > 0; off >>= 1) mx = fmaxf(mx, __shfl_xor(mx, off));
    __shared__ float s4[4];
    if ((tid & 63) == 0) s4[tid >> 6] = mx;
    __syncthreads();
    mx = fmaxf(fmaxf(s4[0], s4[1]), fmaxf(s4[2], s4[3]));

    float sum = 0.f;
    #pragma unroll
    for (int i = 0; i < 8; ++i) {
        loc[i] = __expf(loc[i] - mx);
        sum += loc[i];
    }
    #pragma unroll
    for (int off = 32; off > 0; off >>= 1) sum += __shfl_xor(sum, off);
    __shared__ float s4b[4];
    if ((tid & 63) == 0) s4b[tid >> 6] = sum;
    __syncthreads();
    sum = s4b[0] + s4b[1] + s4b[2] + s4b[3];

    float inv = 1.0f / sum;
    #pragma unroll
    for (int i = 0; i < 8; ++i) row[tid + (i << 8)] = loc[i] * inv;
}

// ---------------------------------------------------------------------------
extern "C" void kernel_launch(void* const* d_in, const int* in_sizes, int n_in,
                              void* d_out, int out_size, void* d_ws, size_t ws_size,
                              hipStream_t stream) {
    const float* shp = (const float*)d_in[0];   // static_hidden [B,H,N]
    const float* dhp = (const float*)d_in[1];   // dynamic_hidden [B,H,N]
    const float* dec = (const float*)d_in[2];   // decoder_hidden [B,H]
    const float* v   = (const float*)d_in[3];   // [H]
    const float* W   = (const float*)d_in[4];   // [H, 3H]
    float* out = (float*)d_out;                 // [B,1,N]

    _Float16* Wf = (_Float16*)d_ws;             // 32768 halves = 64 KB
    float* cbp = (float*)((char*)d_ws + 65536); // 32768 floats = 128 KB

    hipLaunchKernelGGL(prep_w16, dim3(128), dim3(256), 0, stream, W, Wf);
    hipLaunchKernelGGL(prep_c,   dim3(Bn),  dim3(Hd),  0, stream, W, dec, cbp);
    hipLaunchKernelGGL(score_kernel, dim3(Nd / 128, Bn), dim3(256), 0, stream,
                       shp, dhp, Wf, cbp, v, out);
    hipLaunchKernelGGL(softmax_k, dim3(Bn), dim3(256), 0, stream, out);
}